// Round 7
// baseline (404.219 us; speedup 1.0000x reference)
//
#include <hip/hip_runtime.h>

#define NN 20
#define EPG 380
#define BF_BASE 92448   // float index where bf16 transposed-weight region starts

typedef __attribute__((ext_vector_type(8))) short short8;
typedef __attribute__((ext_vector_type(4))) float floatx4;

__device__ __forceinline__ float bf2f(unsigned short u){
  unsigned int x = ((unsigned int)u) << 16;
  return __builtin_bit_cast(float, x);
}
__device__ __forceinline__ unsigned short f2bf(float f){
  unsigned int x = __builtin_bit_cast(unsigned int, f);
  unsigned int r = x + 0x7fffu + ((x >> 16) & 1u);
  return (unsigned short)(r >> 16);
}
// round-half-up bf16 pair pack: 2 adds + 1 v_perm
__device__ __forceinline__ unsigned int pack2bf_rnd(float a, float b){
  unsigned int ua = __builtin_bit_cast(unsigned int, a) + 0x8000u;
  unsigned int ub = __builtin_bit_cast(unsigned int, b) + 0x8000u;
  return __builtin_amdgcn_perm(ub, ua, 0x07060302);  // ua.hi16 | ub.hi16<<16
}
__device__ __forceinline__ float lo_bf(unsigned int u){ return __builtin_bit_cast(float, u << 16); }
__device__ __forceinline__ float hi_bf(unsigned int u){ return __builtin_bit_cast(float, u & 0xffff0000u); }
__device__ __forceinline__ float fsilu(float x){ return x * (1.f/(1.f + __expf(-x))); }
__device__ __forceinline__ float ftanh(float x){ return 1.f - 2.f/(__expf(2.f*x) + 1.f); }

// ---------------- single fused prep kernel ----------------
// bf16 region layout (shorts, from BF_BASE):
//   W1Tn [3][128][64] @0      (BT[c][k]: c<64 -> W1[k][c] (t1), c>=64 -> W1[64+k][c-64] (t2))
//   W2T  [3][64][64]  @24576
//   CW1T [3][64][64]  @36864
//   NW1T [3][64][128] @49152
//   NW2T [3][64][64]  @73728
//   F1T  [64][64]     @86016  (F1T[n][k] = fc1_w[1+k][n])
struct PrepAll {
  const void* fsrc[19];
  const void* w1; const void* w2; const void* cw1;
  const void* nw1; const void* nw2; const void* fc1;
  const unsigned int* masks;
};

__global__ void prep_all(PrepAll a, float* __restrict__ ws){
  const int flag = (a.masks[0] == 0x3F800000u) ? 1 : 0;
  unsigned short* bf = (unsigned short*)(ws + BF_BASE);
  int ty = blockIdx.y;
  int idx = blockIdx.x * blockDim.x + threadIdx.x;

  if (ty < 19){
    static const int nn_[19]  = {512,64,24768,192,12288,192,192,3,24576,192,12288,192,12288,192,192,4160,64,64,1};
    static const int off_[19] = {0,512,576,25344,25536,37824,38016,38208,38224,62800,62992,75280,75472,87760,87952,88144,92304,92368,92432};
    if (idx < nn_[ty]){
      float v;
      if (flag) v = ((const float*)a.fsrc[ty])[idx];
      else      v = bf2f(((const unsigned short*)a.fsrc[ty])[idx]);
      ws[off_[ty] + idx] = v;
    }
    return;
  }
  auto ldbf = [&](const void* p, int i)->unsigned short {
    return flag ? f2bf(((const float*)p)[i]) : ((const unsigned short*)p)[i];
  };
  switch(ty){
    case 19: if (idx<24576){ int l=idx/8192, r=idx-l*8192, c=r>>6, k=r&63;
             int ksrc = (c<64)? k : 64+k; int nsrc = c&63;
             bf[idx] = ldbf(a.w1, l*8256 + ksrc*64 + nsrc); } break;
    case 20: if (idx<12288){ int l=idx>>12, r=idx&4095, n=r>>6, k=r&63;
             bf[24576+idx] = ldbf(a.w2, l*4096+k*64+n); } break;
    case 21: if (idx<12288){ int l=idx>>12, r=idx&4095, n=r>>6, k=r&63;
             bf[36864+idx] = ldbf(a.cw1, l*4096+k*64+n); } break;
    case 22: if (idx<24576){ int l=idx>>13, r=idx&8191, n=r>>7, k=r&127;
             bf[49152+idx] = ldbf(a.nw1, l*8192+k*64+n); } break;
    case 23: if (idx<12288){ int l=idx>>12, r=idx&4095, n=r>>6, k=r&63;
             bf[73728+idx] = ldbf(a.nw2, l*4096+k*64+n); } break;
    case 24: if (idx<4096){ int n=idx>>6, k=idx&63;
             bf[86016+idx] = ldbf(a.fc1, (k+1)*64+n); } break;
    default: break;
  }
}

// ---------------- fused EGNN main: one block per graph ----------------
// Two-pass edge phase (192 edges/pass) to cut LDS -> 3 blocks/CU.
// h kept fp32 in registers of waves 0-3 (node-GEMM layout); cw packed in mstore pad.
__global__ __launch_bounds__(384, 5) void egnn_main(
    const void* __restrict__ obsv,
    const float* __restrict__ ws,
    const unsigned int* __restrict__ masks,
    const void* __restrict__ rnnv,
    void* __restrict__ outv)
{
  __shared__ __align__(16) unsigned short mstore[192*72];  // pass-local m; pad cols 64-65 = cw
  __shared__ __align__(16) char uniA[20*132*4];            // t12f fp32 | obs_lds
  __shared__ __align__(16) char uniB[NN*64*4];             // magg fp32 | (vals4, vals)
  __shared__ __align__(16) unsigned short maggbf[NN*72];
  __shared__ __align__(16) unsigned short n1bf[NN*72];
  __shared__ __align__(16) unsigned short hbf[NN*72];
  __shared__ float x_lds[NN][2];
  __shared__ float x_acc[NN][2];

  float (*t12f)[132]  = (float(*)[132])uniA;
  float (*obs_lds)[8] = (float(*)[8])uniA;
  float (*magg)[64]   = (float(*)[64])uniB;
  float (*vals4)[NN]  = (float(*)[NN])uniB;
  float *vals         = (float*)(uniB + 4*NN*4);

  const int g = blockIdx.x;
  const int tid = threadIdx.x;
  const int flag = (masks[0] == 0x3F800000u) ? 1 : 0;
  const unsigned short* bf = (const unsigned short*)(ws + BF_BASE);

  // ---- rnn_states passthrough ----
  {
    int cnt = flag ? 16 : 8;
    if (tid < cnt){
      const uint4* s = (const uint4*)rnnv;
      uint4* d = (uint4*)((char*)outv + (flag ? 4096 : 2048));
      d[g*cnt + tid] = s[g*cnt + tid];
    }
  }

  // ---- load obs ----
  if (tid < NN*10){
    int node = tid/10, c = tid - node*10;
    float v;
    if (flag) v = ((const float*)obsv)[g*NN*10 + tid];
    else      v = bf2f(((const unsigned short*)obsv)[g*NN*10 + tid]);
    if (c < 2) x_lds[node][c] = v; else obs_lds[node][c-2] = v;
  }
  __syncthreads();

  const int wvi = tid >> 6, ln = tid & 63;
  const int c15 = ln & 15, quad = ln >> 4;

  // ---- embed directly in node-GEMM layout; h fp32 stays in registers ----
  float hreg[2][4];
  if (wvi < 4){
    int col = wvi*16 + c15;
    float ew[8];
    #pragma unroll
    for (int k=0;k<8;k++) ew[k] = ws[k*64 + col];
    float eb = ws[512 + col];
    #pragma unroll
    for (int mt=0;mt<2;mt++)
      #pragma unroll
      for (int reg=0;reg<4;reg++){
        int r = mt*16 + quad*4 + reg;
        if (r < NN){
          float s = eb;
          #pragma unroll
          for (int k=0;k<8;k++) s += obs_lds[r][k]*ew[k];
          hreg[mt][reg] = s;
          hbf[r*72 + col] = f2bf(s);
        }
      }
  }
  __syncthreads();

  // ---- per-(pass,tile) edge node indices ----
  int niA[2][2], njA[2][2];
  #pragma unroll
  for (int p=0;p<2;p++)
    #pragma unroll
    for (int et=0;et<2;et++){
      int e = p*192 + wvi*32 + et*16 + c15;
      int ec = e < EPG ? e : (EPG-1);
      int ii = ec/19, j2 = ec - ii*19;
      niA[p][et] = ii; njA[p][et] = j2 + (j2 >= ii ? 1 : 0);
    }

  for (int l=0; l<3; l++){
    const float* W1  = ws + 576   + l*129*64;     // fp32; only row 128 used
    const float* B1  = ws + 25344 + l*64;
    const float* B2  = ws + 37824 + l*64;
    const float* AW  = ws + 38016 + l*64;
    const float* ABp = ws + 38208 + l;
    const float* NB1 = ws + 62800 + l*64;
    const float* NB2 = ws + 75280 + l*64;
    const float* CB1 = ws + 87760 + l*64;
    const float* CW2 = ws + 87952 + l*64;
    const unsigned short* gW1Tn = bf + l*8192;
    const unsigned short* gW2T  = bf + 24576 + l*4096;
    const unsigned short* gCW1T = bf + 36864 + l*4096;
    const unsigned short* gNW1T = bf + 49152 + l*8192;
    const unsigned short* gNW2T = bf + 73728 + l*4096;

    // ===== t-GEMM: t12 = h @ [W1top|W1bot] (+b1 on t1) : 16 jobs / 6 waves =====
    for (int job = wvi; job < 16; job += 6){
      int ct = job >> 1, mt = job & 1;
      int col = ct*16 + c15;
      float binit = (ct < 4) ? B1[col] : 0.f;
      floatx4 accm = floatx4{binit,binit,binit,binit};
      #pragma unroll
      for (int kc=0;kc<2;kc++){
        short8 bfr = *(const short8*)&gW1Tn[col*64 + kc*32 + quad*8];
        int m = mt*16 + c15;
        int node = m < NN ? m : NN-1;
        short8 afr = *(const short8*)&hbf[node*72 + kc*32 + quad*8];
        accm = __builtin_amdgcn_mfma_f32_16x16x32_bf16(afr, bfr, accm, 0,0,0);
      }
      #pragma unroll
      for (int reg=0;reg<4;reg++){
        int r = mt*16 + quad*4 + reg;
        if (r < NN) t12f[r][col] = accm[reg];
      }
    }
    __syncthreads();

    // ===== two edge passes =====
    #pragma unroll
    for (int p=0;p<2;p++){
      floatx4 acc[4][2];   // [ct][et]
      float cn0o=0.f, cn1o=0.f;

      // ---- m1 = silu(t1[i] + t2[j] + radial*W1[128]) -> mstore ----
      {
        float rad[2];
        #pragma unroll
        for (int et=0;et<2;et++){
          float dx = x_lds[niA[p][et]][0] - x_lds[njA[p][et]][0];
          float dy = x_lds[niA[p][et]][1] - x_lds[njA[p][et]][1];
          float r2 = dx*dx + dy*dy;
          rad[et] = r2;
          float ri = 1.f/(sqrtf(r2) + 1e-8f);
          if (et == quad){ cn0o = dx*ri; cn1o = dy*ri; }  // own edge (quad<2)
        }
        floatx4 w1r4[4];
        #pragma unroll
        for (int ct=0;ct<4;ct++) w1r4[ct] = *(const floatx4*)(W1 + 8192 + ct*16 + quad*4);
        #pragma unroll
        for (int et=0;et<2;et++){
          const float* t1r = t12f[niA[p][et]];
          const float* t2r = t12f[njA[p][et]] + 64;
          int row = (wvi*32 + et*16 + c15)*72 + quad*4;
          #pragma unroll
          for (int ct=0;ct<4;ct++){
            floatx4 ta = *(const floatx4*)(t1r + ct*16 + quad*4);
            floatx4 tb = *(const floatx4*)(t2r + ct*16 + quad*4);
            float v0 = fsilu(ta[0] + tb[0] + rad[et]*w1r4[ct][0]);
            float v1 = fsilu(ta[1] + tb[1] + rad[et]*w1r4[ct][1]);
            float v2 = fsilu(ta[2] + tb[2] + rad[et]*w1r4[ct][2]);
            float v3 = fsilu(ta[3] + tb[3] + rad[et]*w1r4[ct][3]);
            *(uint2*)&mstore[row + ct*16] = uint2{pack2bf_rnd(v0,v1), pack2bf_rnd(v2,v3)};
          }
        }
      }

      // ---- GEMM2^T + attention gate ----
      #pragma unroll
      for (int ct=0;ct<4;ct++){
        floatx4 b4 = *(const floatx4*)(B2 + ct*16 + quad*4);
        #pragma unroll
        for (int et=0;et<2;et++) acc[ct][et] = b4;
      }
      #pragma unroll
      for (int kc=0;kc<2;kc++){
        short8 a[4], b[2];
        #pragma unroll
        for (int ct=0;ct<4;ct++)
          a[ct] = *(const short8*)&gW2T[(ct*16+c15)*64 + kc*32 + quad*8];
        #pragma unroll
        for (int et=0;et<2;et++)
          b[et] = *(const short8*)&mstore[(wvi*32+et*16+c15)*72 + kc*32 + quad*8];
        #pragma unroll
        for (int ct=0;ct<4;ct++)
          #pragma unroll
          for (int et=0;et<2;et++)
            acc[ct][et] = __builtin_amdgcn_mfma_f32_16x16x32_bf16(a[ct], b[et], acc[ct][et], 0,0,0);
      }
      {
        floatx4 aw4[4];
        #pragma unroll
        for (int ct=0;ct<4;ct++) aw4[ct] = *(const floatx4*)(AW + ct*16 + quad*4);
        float ab = ABp[0];
        #pragma unroll
        for (int et=0;et<2;et++){
          float pdot = 0.f;
          #pragma unroll
          for (int ct=0;ct<4;ct++)
            #pragma unroll
            for (int reg=0;reg<4;reg++){
              float v = fsilu(acc[ct][et][reg]);
              acc[ct][et][reg] = v;
              pdot += v*aw4[ct][reg];
            }
          pdot += __shfl_xor(pdot, 16);
          pdot += __shfl_xor(pdot, 32);
          float sg = 1.f/(1.f+__expf(-(pdot+ab)));
          int row = (wvi*32 + et*16 + c15)*72 + quad*4;
          #pragma unroll
          for (int ct=0;ct<4;ct++){
            float v0 = acc[ct][et][0]*sg, v1 = acc[ct][et][1]*sg;
            float v2 = acc[ct][et][2]*sg, v3 = acc[ct][et][3]*sg;
            *(uint2*)&mstore[row + ct*16] = uint2{pack2bf_rnd(v0,v1), pack2bf_rnd(v2,v3)};
          }
        }
      }

      // ---- GEMM3^T: silu, dot CW2, tanh -> cw into mstore pad ----
      #pragma unroll
      for (int ct=0;ct<4;ct++){
        floatx4 b4 = *(const floatx4*)(CB1 + ct*16 + quad*4);
        #pragma unroll
        for (int et=0;et<2;et++) acc[ct][et] = b4;
      }
      #pragma unroll
      for (int kc=0;kc<2;kc++){
        short8 a[4], b[2];
        #pragma unroll
        for (int ct=0;ct<4;ct++)
          a[ct] = *(const short8*)&gCW1T[(ct*16+c15)*64 + kc*32 + quad*8];
        #pragma unroll
        for (int et=0;et<2;et++)
          b[et] = *(const short8*)&mstore[(wvi*32+et*16+c15)*72 + kc*32 + quad*8];
        #pragma unroll
        for (int ct=0;ct<4;ct++)
          #pragma unroll
          for (int et=0;et<2;et++)
            acc[ct][et] = __builtin_amdgcn_mfma_f32_16x16x32_bf16(a[ct], b[et], acc[ct][et], 0,0,0);
      }
      {
        floatx4 cw24[4];
        #pragma unroll
        for (int ct=0;ct<4;ct++) cw24[ct] = *(const floatx4*)(CW2 + ct*16 + quad*4);
        float wsel = 0.f;
        #pragma unroll
        for (int et=0;et<2;et++){
          float pdot = 0.f;
          #pragma unroll
          for (int ct=0;ct<4;ct++)
            #pragma unroll
            for (int reg=0;reg<4;reg++)
              pdot += fsilu(acc[ct][et][reg])*cw24[ct][reg];
          pdot += __shfl_xor(pdot, 16);
          pdot += __shfl_xor(pdot, 32);
          if (et == quad) wsel = ftanh(pdot);
        }
        if (quad < 2){
          int ro = wvi*32 + quad*16 + c15;
          *(unsigned int*)&mstore[ro*72 + 64] = pack2bf_rnd(cn0o*wsel, cn1o*wsel);
        }
      }
      __syncthreads();

      // ---- per-pass aggregation (m and cw), pass-partial ----
      for (int job = tid; job < 640; job += 384){
        int node = job >> 5, pr = job & 31;
        int qlo = max(0, p*192 - node*19);
        int qhi = min(19, p*192 + 192 - node*19);
        float s0=0.f, s1=0.f;
        for (int q=qlo; q<qhi; q++){
          int row = node*19 + q - p*192;
          unsigned int u = *(const unsigned int*)&mstore[row*72 + pr*2];
          s0 += lo_bf(u); s1 += hi_bf(u);
        }
        if (p == 0){
          if (node < 10) *(unsigned int*)&maggbf[node*72 + pr*2] = pack2bf_rnd(s0,s1);
          else if (node == 10){ magg[10][pr*2] = s0; magg[10][pr*2+1] = s1; }
        } else {
          if (node == 10){
            s0 += magg[10][pr*2]; s1 += magg[10][pr*2+1];
            *(unsigned int*)&maggbf[node*72 + pr*2] = pack2bf_rnd(s0,s1);
          } else if (node > 10)
            *(unsigned int*)&maggbf[node*72 + pr*2] = pack2bf_rnd(s0,s1);
        }
      }
      if (tid < NN){
        int node = tid;
        int qlo = max(0, p*192 - node*19);
        int qhi = min(19, p*192 + 192 - node*19);
        float s0=0.f, s1=0.f;
        for (int q=qlo; q<qhi; q++){
          int row = node*19 + q - p*192;
          unsigned int u = *(const unsigned int*)&mstore[row*72 + 64];
          s0 += lo_bf(u); s1 += hi_bf(u);
        }
        if (p == 0){ x_acc[node][0] = s0; x_acc[node][1] = s1; }
        else {
          x_lds[node][0] += (x_acc[node][0] + s0)*(1.f/19.f);
          x_lds[node][1] += (x_acc[node][1] + s1)*(1.f/19.f);
        }
      }
      __syncthreads();
    } // passes

    // =========================== NODE GEMM 1 ===========================
    if (wvi < 4){
      int col = wvi*16 + c15;
      floatx4 accm[2];
      { float b = NB1[col]; accm[0] = floatx4{b,b,b,b}; accm[1] = floatx4{b,b,b,b}; }
      #pragma unroll
      for (int kc=0;kc<4;kc++){
        short8 bfr = *(const short8*)&gNW1T[col*128 + kc*32 + quad*8];
        #pragma unroll
        for (int mt=0;mt<2;mt++){
          int m = mt*16 + c15;
          int node = m < NN ? m : NN-1;
          const unsigned short* abuf = (kc<2) ? &hbf[node*72 + kc*32 + quad*8]
                                              : &maggbf[node*72 + (kc-2)*32 + quad*8];
          short8 afr = *(const short8*)abuf;
          accm[mt] = __builtin_amdgcn_mfma_f32_16x16x32_bf16(afr, bfr, accm[mt], 0,0,0);
        }
      }
      #pragma unroll
      for (int mt=0;mt<2;mt++)
        #pragma unroll
        for (int reg=0;reg<4;reg++){
          int r = mt*16 + quad*4 + reg;
          if (r < NN) n1bf[r*72 + col] = f2bf(fsilu(accm[mt][reg]));
        }
    }
    __syncthreads();

    // =========================== NODE GEMM 2 (h residual in regs) ===========================
    if (wvi < 4){
      int col = wvi*16 + c15;
      floatx4 accm[2];
      { float b = NB2[col]; accm[0] = floatx4{b,b,b,b}; accm[1] = floatx4{b,b,b,b}; }
      #pragma unroll
      for (int kc=0;kc<2;kc++){
        short8 bfr = *(const short8*)&gNW2T[col*64 + kc*32 + quad*8];
        #pragma unroll
        for (int mt=0;mt<2;mt++){
          int m = mt*16 + c15;
          int node = m < NN ? m : NN-1;
          short8 afr = *(const short8*)&n1bf[node*72 + kc*32 + quad*8];
          accm[mt] = __builtin_amdgcn_mfma_f32_16x16x32_bf16(afr, bfr, accm[mt], 0,0,0);
        }
      }
      #pragma unroll
      for (int mt=0;mt<2;mt++)
        #pragma unroll
        for (int reg=0;reg<4;reg++){
          int r = mt*16 + quad*4 + reg;
          if (r < NN){
            float hv = hreg[mt][reg] + accm[mt][reg];
            hreg[mt][reg] = hv;
            hbf[r*72 + col] = f2bf(hv);
          }
        }
    }
    __syncthreads();
  }

  // =========================== HEAD ===========================
  {
    const float* F1 = ws + 88144;   // fp32 [65][64]; row 0 = xsq weights
    const float* F1B= ws + 92304;
    const float* F2 = ws + 92368;
    const float* F2B= ws + 92432;
    const unsigned short* gF1T = bf + 86016;

    if (wvi < 4){
      int col = wvi*16 + c15;
      floatx4 accm[2];
      { float b = F1B[col]; accm[0] = floatx4{b,b,b,b}; accm[1] = floatx4{b,b,b,b}; }
      #pragma unroll
      for (int kc=0;kc<2;kc++){
        short8 bfr = *(const short8*)&gF1T[col*64 + kc*32 + quad*8];
        #pragma unroll
        for (int mt=0;mt<2;mt++){
          int m = mt*16 + c15;
          int node = m < NN ? m : NN-1;
          short8 afr = *(const short8*)&hbf[node*72 + kc*32 + quad*8];
          accm[mt] = __builtin_amdgcn_mfma_f32_16x16x32_bf16(afr, bfr, accm[mt], 0,0,0);
        }
      }
      float f1r0 = F1[col];
      float f2v  = F2[col];
      #pragma unroll
      for (int mt=0;mt<2;mt++)
        #pragma unroll
        for (int reg=0;reg<4;reg++){
          int r = mt*16 + quad*4 + reg;
          int rr = r < NN ? r : NN-1;
          float x0 = x_lds[rr][0], x1 = x_lds[rr][1];
          float xsq = x0*x0 + x1*x1;
          float z = ftanh(accm[mt][reg] + xsq*f1r0);
          float pd = z*f2v;
          #pragma unroll
          for (int off=1; off<16; off<<=1) pd += __shfl_xor(pd, off, 16);
          if (c15 == 0 && r < NN) vals4[wvi][r] = pd;
        }
    }
    __syncthreads();
    if (tid < NN)
      vals[tid] = vals4[0][tid]+vals4[1][tid]+vals4[2][tid]+vals4[3][tid] + F2B[0];
    __syncthreads();
    if (tid == 0){
      float s = 0.f;
      #pragma unroll
      for (int i=0;i<NN;i++) s += vals[i];
      float v = s*(1.f/NN);
      if (flag) ((float*)outv)[g] = v;
      else      ((unsigned short*)outv)[g] = f2bf(v);
    }
  }
}

extern "C" void kernel_launch(void* const* d_in, const int* in_sizes, int n_in,
                              void* d_out, int out_size, void* d_ws, size_t ws_size,
                              hipStream_t stream) {
  static const int srcIdx[19] = {3,4,5,6,7,8,9,10,11,12,13,14,15,16,17,18,19,20,21};
  float* ws = (float*)d_ws;

  PrepAll pa;
  for (int i=0;i<19;i++) pa.fsrc[i] = d_in[srcIdx[i]];
  pa.w1  = d_in[5];  pa.w2  = d_in[7];  pa.cw1 = d_in[15];
  pa.nw1 = d_in[11]; pa.nw2 = d_in[13]; pa.fc1 = d_in[18];
  pa.masks = (const unsigned int*)d_in[2];

  prep_all<<<dim3(102,25), 256, 0, stream>>>(pa, ws);
  egnn_main<<<1024, 384, 0, stream>>>(d_in[0], ws,
                                      (const unsigned int*)d_in[2], d_in[1], d_out);
}

// Round 8
// 390.088 us; speedup vs baseline: 1.0362x; 1.0362x over previous
//
#include <hip/hip_runtime.h>

#define NN 20
#define EPG 380
#define BF_BASE 92448   // float index where bf16 transposed-weight region starts

typedef __attribute__((ext_vector_type(8))) short short8;
typedef __attribute__((ext_vector_type(4))) float floatx4;

__device__ __forceinline__ float bf2f(unsigned short u){
  unsigned int x = ((unsigned int)u) << 16;
  return __builtin_bit_cast(float, x);
}
__device__ __forceinline__ unsigned short f2bf(float f){
  unsigned int x = __builtin_bit_cast(unsigned int, f);
  unsigned int r = x + 0x7fffu + ((x >> 16) & 1u);
  return (unsigned short)(r >> 16);
}
// round-half-up bf16 pair pack: 2 adds + 1 v_perm
__device__ __forceinline__ unsigned int pack2bf_rnd(float a, float b){
  unsigned int ua = __builtin_bit_cast(unsigned int, a) + 0x8000u;
  unsigned int ub = __builtin_bit_cast(unsigned int, b) + 0x8000u;
  return __builtin_amdgcn_perm(ub, ua, 0x07060302);  // ua.hi16 | ub.hi16<<16
}
__device__ __forceinline__ float lo_bf(unsigned int u){ return __builtin_bit_cast(float, u << 16); }
__device__ __forceinline__ float hi_bf(unsigned int u){ return __builtin_bit_cast(float, u & 0xffff0000u); }
__device__ __forceinline__ float fsilu(float x){ return x * (1.f/(1.f + __expf(-x))); }
__device__ __forceinline__ float ftanh(float x){ return 1.f - 2.f/(__expf(2.f*x) + 1.f); }

// ---------------- single fused prep kernel ----------------
// bf16 region layout (shorts, from BF_BASE):
//   W1Tn [3][128][64] @0      (BT[c][k]: c<64 -> W1[k][c] (t1), c>=64 -> W1[64+k][c-64] (t2))
//   W2T  [3][64][64]  @24576
//   CW1T [3][64][64]  @36864
//   NW1T [3][64][128] @49152
//   NW2T [3][64][64]  @73728
//   F1T  [64][64]     @86016  (F1T[n][k] = fc1_w[1+k][n])
struct PrepAll {
  const void* fsrc[19];
  const void* w1; const void* w2; const void* cw1;
  const void* nw1; const void* nw2; const void* fc1;
  const unsigned int* masks;
};

__global__ void prep_all(PrepAll a, float* __restrict__ ws){
  const int flag = (a.masks[0] == 0x3F800000u) ? 1 : 0;
  unsigned short* bf = (unsigned short*)(ws + BF_BASE);
  int ty = blockIdx.y;
  int idx = blockIdx.x * blockDim.x + threadIdx.x;

  if (ty < 19){
    static const int nn_[19]  = {512,64,24768,192,12288,192,192,3,24576,192,12288,192,12288,192,192,4160,64,64,1};
    static const int off_[19] = {0,512,576,25344,25536,37824,38016,38208,38224,62800,62992,75280,75472,87760,87952,88144,92304,92368,92432};
    if (idx < nn_[ty]){
      float v;
      if (flag) v = ((const float*)a.fsrc[ty])[idx];
      else      v = bf2f(((const unsigned short*)a.fsrc[ty])[idx]);
      ws[off_[ty] + idx] = v;
    }
    return;
  }
  auto ldbf = [&](const void* p, int i)->unsigned short {
    return flag ? f2bf(((const float*)p)[i]) : ((const unsigned short*)p)[i];
  };
  switch(ty){
    case 19: if (idx<24576){ int l=idx/8192, r=idx-l*8192, c=r>>6, k=r&63;
             int ksrc = (c<64)? k : 64+k; int nsrc = c&63;
             bf[idx] = ldbf(a.w1, l*8256 + ksrc*64 + nsrc); } break;
    case 20: if (idx<12288){ int l=idx>>12, r=idx&4095, n=r>>6, k=r&63;
             bf[24576+idx] = ldbf(a.w2, l*4096+k*64+n); } break;
    case 21: if (idx<12288){ int l=idx>>12, r=idx&4095, n=r>>6, k=r&63;
             bf[36864+idx] = ldbf(a.cw1, l*4096+k*64+n); } break;
    case 22: if (idx<24576){ int l=idx>>13, r=idx&8191, n=r>>7, k=r&127;
             bf[49152+idx] = ldbf(a.nw1, l*8192+k*64+n); } break;
    case 23: if (idx<12288){ int l=idx>>12, r=idx&4095, n=r>>6, k=r&63;
             bf[73728+idx] = ldbf(a.nw2, l*4096+k*64+n); } break;
    case 24: if (idx<4096){ int n=idx>>6, k=idx&63;
             bf[86016+idx] = ldbf(a.fc1, (k+1)*64+n); } break;
    default: break;
  }
}

// ---------------- fused EGNN main: one block per graph, 256 threads ----------------
// Three-pass edge phase (128 edges/pass); magg/x aggregation in registers across
// passes; LDS ~38 KB + natural VGPR <=128 -> 4 blocks/CU, whole grid resident.
__global__ __launch_bounds__(256, 4) void egnn_main(
    const void* __restrict__ obsv,
    const float* __restrict__ ws,
    const unsigned int* __restrict__ masks,
    const void* __restrict__ rnnv,
    void* __restrict__ outv)
{
  __shared__ __align__(16) unsigned short mstore[128*72];  // pass-local m; cols 64-65 = cw
  __shared__ __align__(16) char uniA[20*132*4];            // t12f fp32 | obs_lds | (vals4,vals)
  __shared__ __align__(16) unsigned short maggbf[NN*72];
  __shared__ __align__(16) unsigned short n1bf[NN*72];
  __shared__ __align__(16) unsigned short hbf[NN*72];
  __shared__ float x_lds[NN][2];

  float (*t12f)[132]  = (float(*)[132])uniA;
  float (*obs_lds)[8] = (float(*)[8])uniA;
  float (*vals4)[NN]  = (float(*)[NN])uniA;
  float *vals         = (float*)uniA + 4*NN;

  const int g = blockIdx.x;
  const int tid = threadIdx.x;
  const int flag = (masks[0] == 0x3F800000u) ? 1 : 0;
  const unsigned short* bf = (const unsigned short*)(ws + BF_BASE);

  // ---- rnn_states passthrough ----
  {
    int cnt = flag ? 16 : 8;
    if (tid < cnt){
      const uint4* s = (const uint4*)rnnv;
      uint4* d = (uint4*)((char*)outv + (flag ? 4096 : 2048));
      d[g*cnt + tid] = s[g*cnt + tid];
    }
  }

  // ---- load obs ----
  if (tid < NN*10){
    int node = tid/10, c = tid - node*10;
    float v;
    if (flag) v = ((const float*)obsv)[g*NN*10 + tid];
    else      v = bf2f(((const unsigned short*)obsv)[g*NN*10 + tid]);
    if (c < 2) x_lds[node][c] = v; else obs_lds[node][c-2] = v;
  }
  __syncthreads();

  const int wvi = tid >> 6, ln = tid & 63;
  const int c15 = ln & 15, quad = ln >> 4;

  // ---- embed directly in node-GEMM layout; h fp32 stays in registers ----
  float hreg[2][4];
  {
    int col = wvi*16 + c15;
    float ew[8];
    #pragma unroll
    for (int k=0;k<8;k++) ew[k] = ws[k*64 + col];
    float eb = ws[512 + col];
    #pragma unroll
    for (int mt=0;mt<2;mt++)
      #pragma unroll
      for (int reg=0;reg<4;reg++){
        int r = mt*16 + quad*4 + reg;
        if (r < NN){
          float s = eb;
          #pragma unroll
          for (int k=0;k<8;k++) s += obs_lds[r][k]*ew[k];
          hreg[mt][reg] = s;
          hbf[r*72 + col] = f2bf(s);
        }
      }
  }
  __syncthreads();

  for (int l=0; l<3; l++){
    const float* W1  = ws + 576   + l*129*64;     // fp32; only row 128 used
    const float* B1  = ws + 25344 + l*64;
    const float* B2  = ws + 37824 + l*64;
    const float* AW  = ws + 38016 + l*64;
    const float* ABp = ws + 38208 + l;
    const float* NB1 = ws + 62800 + l*64;
    const float* NB2 = ws + 75280 + l*64;
    const float* CB1 = ws + 87760 + l*64;
    const float* CW2 = ws + 87952 + l*64;
    const unsigned short* gW1Tn = bf + l*8192;
    const unsigned short* gW2T  = bf + 24576 + l*4096;
    const unsigned short* gCW1T = bf + 36864 + l*4096;
    const unsigned short* gNW1T = bf + 49152 + l*8192;
    const unsigned short* gNW2T = bf + 73728 + l*4096;

    // ===== t-GEMM: t12 = h @ [W1top|W1bot] (+b1 on t1) : 16 jobs / 4 waves =====
    for (int job = wvi; job < 16; job += 4){
      int ct = job >> 1, mt = job & 1;
      int col = ct*16 + c15;
      float binit = (ct < 4) ? B1[col] : 0.f;
      floatx4 accm = floatx4{binit,binit,binit,binit};
      #pragma unroll
      for (int kc=0;kc<2;kc++){
        short8 bfr = *(const short8*)&gW1Tn[col*64 + kc*32 + quad*8];
        int m = mt*16 + c15;
        int node = m < NN ? m : NN-1;
        short8 afr = *(const short8*)&hbf[node*72 + kc*32 + quad*8];
        accm = __builtin_amdgcn_mfma_f32_16x16x32_bf16(afr, bfr, accm, 0,0,0);
      }
      #pragma unroll
      for (int reg=0;reg<4;reg++){
        int r = mt*16 + quad*4 + reg;
        if (r < NN) t12f[r][col] = accm[reg];
      }
    }
    __syncthreads();

    // ===== three edge passes; aggregation accumulates in registers =====
    float am0[2] = {0.f,0.f}, am1[2] = {0.f,0.f}, am2[2] = {0.f,0.f};  // m-agg jobs
    float sx0 = 0.f, sx1 = 0.f;                                        // x-agg (tid<20)

    for (int p=0;p<3;p++){
      // per-tile node indices for this pass
      int ni[2], nj[2];
      #pragma unroll
      for (int et=0;et<2;et++){
        int e_ = p*128 + wvi*32 + et*16 + c15;
        int ec = e_ < EPG ? e_ : (EPG-1);
        int ii = ec/19, j2 = ec - ii*19;
        ni[et] = ii; nj[et] = j2 + (j2 >= ii ? 1 : 0);
      }

      floatx4 acc[4][2];   // [ct][et]
      float cn0o=0.f, cn1o=0.f;

      // ---- m1 = silu(t1[i] + t2[j] + radial*W1[128]) -> mstore ----
      {
        float rad[2];
        #pragma unroll
        for (int et=0;et<2;et++){
          float dx = x_lds[ni[et]][0] - x_lds[nj[et]][0];
          float dy = x_lds[ni[et]][1] - x_lds[nj[et]][1];
          float r2 = dx*dx + dy*dy;
          rad[et] = r2;
          float ri = 1.f/(sqrtf(r2) + 1e-8f);
          if (et == quad){ cn0o = dx*ri; cn1o = dy*ri; }  // own edge (quad<2 only)
        }
        floatx4 w1r4[4];
        #pragma unroll
        for (int ct=0;ct<4;ct++) w1r4[ct] = *(const floatx4*)(W1 + 8192 + ct*16 + quad*4);
        #pragma unroll
        for (int et=0;et<2;et++){
          const float* t1r = t12f[ni[et]];
          const float* t2r = t12f[nj[et]] + 64;
          int row = (wvi*32 + et*16 + c15)*72 + quad*4;
          #pragma unroll
          for (int ct=0;ct<4;ct++){
            floatx4 ta = *(const floatx4*)(t1r + ct*16 + quad*4);
            floatx4 tb = *(const floatx4*)(t2r + ct*16 + quad*4);
            float v0 = fsilu(ta[0] + tb[0] + rad[et]*w1r4[ct][0]);
            float v1 = fsilu(ta[1] + tb[1] + rad[et]*w1r4[ct][1]);
            float v2 = fsilu(ta[2] + tb[2] + rad[et]*w1r4[ct][2]);
            float v3 = fsilu(ta[3] + tb[3] + rad[et]*w1r4[ct][3]);
            *(uint2*)&mstore[row + ct*16] = uint2{pack2bf_rnd(v0,v1), pack2bf_rnd(v2,v3)};
          }
        }
      }

      // ---- GEMM2^T + attention gate ----
      #pragma unroll
      for (int ct=0;ct<4;ct++){
        floatx4 b4 = *(const floatx4*)(B2 + ct*16 + quad*4);
        #pragma unroll
        for (int et=0;et<2;et++) acc[ct][et] = b4;
      }
      #pragma unroll
      for (int kc=0;kc<2;kc++){
        short8 a[4], b[2];
        #pragma unroll
        for (int ct=0;ct<4;ct++)
          a[ct] = *(const short8*)&gW2T[(ct*16+c15)*64 + kc*32 + quad*8];
        #pragma unroll
        for (int et=0;et<2;et++)
          b[et] = *(const short8*)&mstore[(wvi*32+et*16+c15)*72 + kc*32 + quad*8];
        #pragma unroll
        for (int ct=0;ct<4;ct++)
          #pragma unroll
          for (int et=0;et<2;et++)
            acc[ct][et] = __builtin_amdgcn_mfma_f32_16x16x32_bf16(a[ct], b[et], acc[ct][et], 0,0,0);
      }
      {
        floatx4 aw4[4];
        #pragma unroll
        for (int ct=0;ct<4;ct++) aw4[ct] = *(const floatx4*)(AW + ct*16 + quad*4);
        float ab = ABp[0];
        #pragma unroll
        for (int et=0;et<2;et++){
          float pdot = 0.f;
          #pragma unroll
          for (int ct=0;ct<4;ct++)
            #pragma unroll
            for (int reg=0;reg<4;reg++){
              float v = fsilu(acc[ct][et][reg]);
              acc[ct][et][reg] = v;
              pdot += v*aw4[ct][reg];
            }
          pdot += __shfl_xor(pdot, 16);
          pdot += __shfl_xor(pdot, 32);
          float sg = 1.f/(1.f+__expf(-(pdot+ab)));
          int row = (wvi*32 + et*16 + c15)*72 + quad*4;
          #pragma unroll
          for (int ct=0;ct<4;ct++){
            float v0 = acc[ct][et][0]*sg, v1 = acc[ct][et][1]*sg;
            float v2 = acc[ct][et][2]*sg, v3 = acc[ct][et][3]*sg;
            *(uint2*)&mstore[row + ct*16] = uint2{pack2bf_rnd(v0,v1), pack2bf_rnd(v2,v3)};
          }
        }
      }

      // ---- GEMM3^T: silu, dot CW2, tanh -> cw into mstore pad ----
      #pragma unroll
      for (int ct=0;ct<4;ct++){
        floatx4 b4 = *(const floatx4*)(CB1 + ct*16 + quad*4);
        #pragma unroll
        for (int et=0;et<2;et++) acc[ct][et] = b4;
      }
      #pragma unroll
      for (int kc=0;kc<2;kc++){
        short8 a[4], b[2];
        #pragma unroll
        for (int ct=0;ct<4;ct++)
          a[ct] = *(const short8*)&gCW1T[(ct*16+c15)*64 + kc*32 + quad*8];
        #pragma unroll
        for (int et=0;et<2;et++)
          b[et] = *(const short8*)&mstore[(wvi*32+et*16+c15)*72 + kc*32 + quad*8];
        #pragma unroll
        for (int ct=0;ct<4;ct++)
          #pragma unroll
          for (int et=0;et<2;et++)
            acc[ct][et] = __builtin_amdgcn_mfma_f32_16x16x32_bf16(a[ct], b[et], acc[ct][et], 0,0,0);
      }
      {
        floatx4 cw24[4];
        #pragma unroll
        for (int ct=0;ct<4;ct++) cw24[ct] = *(const floatx4*)(CW2 + ct*16 + quad*4);
        float wsel = 0.f;
        #pragma unroll
        for (int et=0;et<2;et++){
          float pdot = 0.f;
          #pragma unroll
          for (int ct=0;ct<4;ct++)
            #pragma unroll
            for (int reg=0;reg<4;reg++)
              pdot += fsilu(acc[ct][et][reg])*cw24[ct][reg];
          pdot += __shfl_xor(pdot, 16);
          pdot += __shfl_xor(pdot, 32);
          if (et == quad) wsel = ftanh(pdot);
        }
        if (quad < 2){
          int ro = wvi*32 + quad*16 + c15;
          *(unsigned int*)&mstore[ro*72 + 64] = pack2bf_rnd(cn0o*wsel, cn1o*wsel);
        }
      }
      __syncthreads();

      // ---- per-pass aggregation into registers ----
      {
        auto aggm = [&](int job, float* s){
          int node = job >> 5, pr = job & 31;
          int qlo = p*128 - node*19;       if (qlo < 0) qlo = 0;
          int qhi = p*128 + 128 - node*19; if (qhi > 19) qhi = 19;
          for (int q=qlo; q<qhi; q++){
            unsigned int u = *(const unsigned int*)&mstore[(node*19 + q - p*128)*72 + pr*2];
            s[0] += lo_bf(u); s[1] += hi_bf(u);
          }
          if (p == 2) *(unsigned int*)&maggbf[node*72 + pr*2] = pack2bf_rnd(s[0], s[1]);
        };
        aggm(tid, am0);
        aggm(tid + 256, am1);
        if (tid < 128) aggm(tid + 512, am2);
      }
      if (tid < NN){
        int node = tid;
        int qlo = p*128 - node*19;       if (qlo < 0) qlo = 0;
        int qhi = p*128 + 128 - node*19; if (qhi > 19) qhi = 19;
        for (int q=qlo; q<qhi; q++){
          unsigned int u = *(const unsigned int*)&mstore[(node*19 + q - p*128)*72 + 64];
          sx0 += lo_bf(u); sx1 += hi_bf(u);
        }
        if (p == 2){
          x_lds[node][0] += sx0*(1.f/19.f);
          x_lds[node][1] += sx1*(1.f/19.f);
        }
      }
      __syncthreads();
    } // passes

    // =========================== NODE GEMM 1 ===========================
    {
      int col = wvi*16 + c15;
      floatx4 accm[2];
      { float b = NB1[col]; accm[0] = floatx4{b,b,b,b}; accm[1] = floatx4{b,b,b,b}; }
      #pragma unroll
      for (int kc=0;kc<4;kc++){
        short8 bfr = *(const short8*)&gNW1T[col*128 + kc*32 + quad*8];
        #pragma unroll
        for (int mt=0;mt<2;mt++){
          int m = mt*16 + c15;
          int node = m < NN ? m : NN-1;
          const unsigned short* abuf = (kc<2) ? &hbf[node*72 + kc*32 + quad*8]
                                              : &maggbf[node*72 + (kc-2)*32 + quad*8];
          short8 afr = *(const short8*)abuf;
          accm[mt] = __builtin_amdgcn_mfma_f32_16x16x32_bf16(afr, bfr, accm[mt], 0,0,0);
        }
      }
      __syncthreads();   // maggbf/hbf reads done before n1bf writes (aliasing-safe ordering)
      #pragma unroll
      for (int mt=0;mt<2;mt++)
        #pragma unroll
        for (int reg=0;reg<4;reg++){
          int r = mt*16 + quad*4 + reg;
          if (r < NN) n1bf[r*72 + col] = f2bf(fsilu(accm[mt][reg]));
        }
    }
    __syncthreads();

    // =========================== NODE GEMM 2 (h residual in regs) ===========================
    {
      int col = wvi*16 + c15;
      floatx4 accm[2];
      { float b = NB2[col]; accm[0] = floatx4{b,b,b,b}; accm[1] = floatx4{b,b,b,b}; }
      #pragma unroll
      for (int kc=0;kc<2;kc++){
        short8 bfr = *(const short8*)&gNW2T[col*64 + kc*32 + quad*8];
        #pragma unroll
        for (int mt=0;mt<2;mt++){
          int m = mt*16 + c15;
          int node = m < NN ? m : NN-1;
          short8 afr = *(const short8*)&n1bf[node*72 + kc*32 + quad*8];
          accm[mt] = __builtin_amdgcn_mfma_f32_16x16x32_bf16(afr, bfr, accm[mt], 0,0,0);
        }
      }
      #pragma unroll
      for (int mt=0;mt<2;mt++)
        #pragma unroll
        for (int reg=0;reg<4;reg++){
          int r = mt*16 + quad*4 + reg;
          if (r < NN){
            float hv = hreg[mt][reg] + accm[mt][reg];
            hreg[mt][reg] = hv;
            hbf[r*72 + col] = f2bf(hv);
          }
        }
    }
    __syncthreads();
  }

  // =========================== HEAD ===========================
  {
    const float* F1 = ws + 88144;   // fp32 [65][64]; row 0 = xsq weights
    const float* F1B= ws + 92304;
    const float* F2 = ws + 92368;
    const float* F2B= ws + 92432;
    const unsigned short* gF1T = bf + 86016;

    int col = wvi*16 + c15;
    floatx4 accm[2];
    { float b = F1B[col]; accm[0] = floatx4{b,b,b,b}; accm[1] = floatx4{b,b,b,b}; }
    #pragma unroll
    for (int kc=0;kc<2;kc++){
      short8 bfr = *(const short8*)&gF1T[col*64 + kc*32 + quad*8];
      #pragma unroll
      for (int mt=0;mt<2;mt++){
        int m = mt*16 + c15;
        int node = m < NN ? m : NN-1;
        short8 afr = *(const short8*)&hbf[node*72 + kc*32 + quad*8];
        accm[mt] = __builtin_amdgcn_mfma_f32_16x16x32_bf16(afr, bfr, accm[mt], 0,0,0);
      }
    }
    float f1r0 = F1[col];
    float f2v  = F2[col];
    __syncthreads();   // t12f region reuse as vals4 below
    #pragma unroll
    for (int mt=0;mt<2;mt++)
      #pragma unroll
      for (int reg=0;reg<4;reg++){
        int r = mt*16 + quad*4 + reg;
        int rr = r < NN ? r : NN-1;
        float x0 = x_lds[rr][0], x1 = x_lds[rr][1];
        float xsq = x0*x0 + x1*x1;
        float z = ftanh(accm[mt][reg] + xsq*f1r0);
        float pd = z*f2v;
        #pragma unroll
        for (int off=1; off<16; off<<=1) pd += __shfl_xor(pd, off, 16);
        if (c15 == 0 && r < NN) vals4[wvi][r] = pd;
      }
    __syncthreads();
    if (tid < NN)
      vals[tid] = vals4[0][tid]+vals4[1][tid]+vals4[2][tid]+vals4[3][tid] + F2B[0];
    __syncthreads();
    if (tid == 0){
      float s = 0.f;
      #pragma unroll
      for (int i=0;i<NN;i++) s += vals[i];
      float v = s*(1.f/NN);
      if (flag) ((float*)outv)[g] = v;
      else      ((unsigned short*)outv)[g] = f2bf(v);
    }
  }
}

extern "C" void kernel_launch(void* const* d_in, const int* in_sizes, int n_in,
                              void* d_out, int out_size, void* d_ws, size_t ws_size,
                              hipStream_t stream) {
  static const int srcIdx[19] = {3,4,5,6,7,8,9,10,11,12,13,14,15,16,17,18,19,20,21};
  float* ws = (float*)d_ws;

  PrepAll pa;
  for (int i=0;i<19;i++) pa.fsrc[i] = d_in[srcIdx[i]];
  pa.w1  = d_in[5];  pa.w2  = d_in[7];  pa.cw1 = d_in[15];
  pa.nw1 = d_in[11]; pa.nw2 = d_in[13]; pa.fc1 = d_in[18];
  pa.masks = (const unsigned int*)d_in[2];

  prep_all<<<dim3(102,25), 256, 0, stream>>>(pa, ws);
  egnn_main<<<1024, 256, 0, stream>>>(d_in[0], ws,
                                      (const unsigned int*)d_in[2], d_in[1], d_out);
}